// Round 11
// baseline (334.900 us; speedup 1.0000x reference)
//
#include <hip/hip_runtime.h>

// Problem constants
#define SEQ   2048
#define BATCH 16
#define CINCH 512
#define HDIM  512
#define NDIM  1536            // 3*H
#define TBM   (SEQ*BATCH)     // 32768 = GEMM M
#define KRED  1024            // Cin*K = GEMM K
#define NCH   32              // scan chunks (R2-proven; NCH=64 measured worse)
#define CHL   64              // chunk length (NCH*CHL == SEQ)
#define NCOL  8192            // B*H chains

typedef unsigned short ushort_t;
typedef __bf16 bf16x8 __attribute__((ext_vector_type(8)));
typedef unsigned short u16x8 __attribute__((ext_vector_type(8)));
typedef unsigned short u16x4 __attribute__((ext_vector_type(4)));
typedef float f32x4 __attribute__((ext_vector_type(4)));

__device__ __forceinline__ float bf2f(ushort_t u) {
    return __uint_as_float(((unsigned int)u) << 16);
}
__device__ __forceinline__ ushort_t f2bf(float x) {
    unsigned int u = __float_as_uint(x);
    unsigned int r = u + 0x7fffu + ((u >> 16) & 1u);   // round-to-nearest-even
    return (ushort_t)(r >> 16);
}

// ---------------------------------------------------------------------------
// Kernel 1: fused prep — cast x (fp32 -> bf16, with BATCH*CINCH zero prefix)
// and repack W (3H, Cin, 2) -> Wb (3H, 1024), one launch. x/W are last-use
// reads -> nontemporal.
// ---------------------------------------------------------------------------
#define CAST_BLOCKS 16392
__global__ void prep_kernel(const float* __restrict__ x, ushort_t* __restrict__ xb,
                            const float* __restrict__ W, ushort_t* __restrict__ wb) {
    if (blockIdx.x < CAST_BLOCKS) {
        int i = blockIdx.x * 256 + threadIdx.x;
        int e = i * 4;
        ushort4 r;
        if (e < BATCH * CINCH) {
            r.x = 0; r.y = 0; r.z = 0; r.w = 0;
        } else {
            f32x4 v = __builtin_nontemporal_load((const f32x4*)(x + (e - BATCH * CINCH)));
            r.x = f2bf(v[0]); r.y = f2bf(v[1]); r.z = f2bf(v[2]); r.w = f2bf(v[3]);
        }
        *(ushort4*)(xb + e) = r;
    } else {
        int i = (blockIdx.x - CAST_BLOCKS) * 256 + threadIdx.x;
        int o  = i >> 10;
        int r  = i & 1023;
        int k  = r >> 9;
        int ci = r & 511;
        wb[i] = f2bf(__builtin_nontemporal_load(W + o * 1024 + ci * 2 + k));
    }
}

// ---------------------------------------------------------------------------
// Kernel 2: GEMM + bias + activation -> bf16 gates z/f/o, each [T*B][H].
// Champion 2-barrier schedule (R0/R6/R10-proven) at 256x256 tile, BK=64,
// 8 waves (2Mx4N), 16x16x32 MFMA, XOR-swizzled LDS, global_load_lds width=16
// for BOTH A and B, XCD-chunked N-fastest swizzle (R10: FETCH 135->66 MB).
// Rationale: K-loop is LDS-pipe-bound (~96KB LDS traffic per 1M-MAC at 128^2);
// 256^2 cuts LDS bytes/FLOP 1.5x while keeping 2 blocks/CU (16 waves).
// NOT the failed variants: no 8-phase (R2:138), no B-in-reg (R4/R5: 204/286).
// ---------------------------------------------------------------------------
__device__ __forceinline__ void load_lds_16B(const ushort_t* g, ushort_t* l) {
    auto* gp = reinterpret_cast<const __attribute__((address_space(1))) unsigned int*>(
        reinterpret_cast<uintptr_t>(g));
    auto* lp = reinterpret_cast<__attribute__((address_space(3))) unsigned int*>(
        reinterpret_cast<uintptr_t>(l));
    __builtin_amdgcn_global_load_lds(gp, lp, 16, 0, 0);
}

__global__ __launch_bounds__(512) void gemm_gates_kernel(
    const ushort_t* __restrict__ xb, const ushort_t* __restrict__ wb,
    const float* __restrict__ bias,
    ushort_t* __restrict__ zb, ushort_t* __restrict__ fb, ushort_t* __restrict__ ob) {

    __shared__ ushort_t smem[2 * 256 * 64];   // 64 KB: As/Bs in K-loop; 128x256 epilogue half
    ushort_t* As = smem;                      // 256 x 64
    ushort_t* Bs = smem + 256 * 64;

    const int tid  = threadIdx.x;
    const int w    = tid >> 6;       // 0..7
    const int lane = tid & 63;
    const int quad = lane >> 4;
    const int l15  = lane & 15;
    const int wm   = w >> 2;         // 0..1 (M half)
    const int wn   = w & 3;          // 0..3 (N quarter)

    // XCD-chunked bijective swizzle (768 % 8 == 0), N-tile fastest in a chunk:
    // XCD k gets 96 blocks = 16 A-panels x 6 N-tiles.
    const int bid = blockIdx.x;
    const int swz = (bid & 7) * 96 + (bid >> 3);
    const int mBase = (swz / 6) * 256;
    const int nBase = (swz % 6) * 256;

    const int srow = lane >> 3;
    const int scb  = lane & 7;

    f32x4 acc[8][4];
#pragma unroll
    for (int i = 0; i < 8; ++i)
#pragma unroll
        for (int j = 0; j < 4; ++j)
            acc[i][j] = (f32x4){0.f, 0.f, 0.f, 0.f};

    for (int kt = 0; kt < 16; ++kt) {
        __syncthreads();
        const long aOff = (kt < 8) ? (long)kt * 64 : (long)16 * 512 + (long)(kt - 8) * 64;
#pragma unroll
        for (int i = 0; i < 4; ++i) {
            const int row = w * 32 + i * 8 + srow;       // 0..255 across 8 waves
            const int cbd = scb ^ (row & 7);
            const ushort_t* ga = xb + (long)(mBase + row) * 512 + aOff + cbd * 8;
            load_lds_16B(ga, &As[(w * 32 + i * 8) * 64]);
            const ushort_t* gb = wb + (long)(nBase + row) * 1024 + kt * 64 + cbd * 8;
            load_lds_16B(gb, &Bs[(w * 32 + i * 8) * 64]);
        }
        __syncthreads();

#pragma unroll
        for (int ks = 0; ks < 2; ++ks) {
            bf16x8 af[8], bfr[4];
            const int cbd = ks * 4 + quad;
#pragma unroll
            for (int mt = 0; mt < 8; ++mt) {
                int ml  = wm * 128 + mt * 16 + l15;
                int off = ml * 64 + ((cbd ^ (ml & 7)) * 8);
                af[mt] = __builtin_bit_cast(bf16x8, *(const u16x8*)(&As[off]));
            }
#pragma unroll
            for (int nt = 0; nt < 4; ++nt) {
                int nl  = wn * 64 + nt * 16 + l15;
                int off = nl * 64 + ((cbd ^ (nl & 7)) * 8);
                bfr[nt] = __builtin_bit_cast(bf16x8, *(const u16x8*)(&Bs[off]));
            }
#pragma unroll
            for (int mt = 0; mt < 8; ++mt)
#pragma unroll
                for (int nt = 0; nt < 4; ++nt)
                    acc[mt][nt] = __builtin_amdgcn_mfma_f32_16x16x32_bf16(
                        af[mt], bfr[nt], acc[mt][nt], 0, 0, 0);
        }
    }

    // ---- Epilogue: two 128-row halves through the 64 KB LDS (R4-verified)
    const int gate = nBase >> 9;            // block-uniform (256-tile within a gate)
    const int hb   = nBase & 511;
    ushort_t* outp = (gate == 0) ? zb : (gate == 1) ? fb : ob;
    const int lb    = tid & 31;
    const int mrow0 = tid >> 5;             // 0..15

#pragma unroll
    for (int h = 0; h < 2; ++h) {
        __syncthreads();
        if (wm == h) {
#pragma unroll
            for (int nt = 0; nt < 4; ++nt) {
                const int n_local = wn * 64 + nt * 16 + l15;
                const float bv = bias[nBase + n_local];
#pragma unroll
                for (int mt = 0; mt < 8; ++mt) {
#pragma unroll
                    for (int r = 0; r < 4; ++r) {
                        const int mrow = mt * 16 + quad * 4 + r;   // 0..127 in half
                        float g = acc[mt][nt][r] + bv;
                        float a;
                        if (gate == 0) {
                            float e = __expf(-2.f * fabsf(g));
                            float t = (1.f - e) / (1.f + e);
                            a = copysignf(t, g);
                        } else {
                            a = 1.f / (1.f + __expf(-g));
                        }
                        const int phys = ((n_local >> 3) ^ (mrow & 7)) * 8 + (n_local & 7);
                        smem[mrow * 256 + phys] = f2bf(a);
                    }
                }
            }
        }
        __syncthreads();
#pragma unroll
        for (int s = 0; s < 8; ++s) {
            const int mr = s * 16 + mrow0;                 // 0..127
            const int m_local = h * 128 + mr;
            u16x8 v = *(const u16x8*)(&smem[mr * 256 + ((lb ^ (mr & 7)) * 8)]);
            *(u16x8*)(outp + (long)(mBase + m_local) * 512 + hb + lb * 8) = v;
        }
    }
}

// ---------------------------------------------------------------------------
// Scan, chunked-parallel, TWO passes (prefix fused into apply) — R8-proven.
// ---------------------------------------------------------------------------
__device__ __forceinline__ void scan_step(float z, float f, float& A, float& Bv) {
    Bv = f * Bv + (1.f - f) * z;
    A *= f;
}

__device__ __forceinline__ u16x4 ntload_u4(const ushort_t* p) {
    return __builtin_nontemporal_load((const u16x4*)p);
}

__global__ __launch_bounds__(256) void scan_compose(
    const ushort_t* __restrict__ zb, const ushort_t* __restrict__ fb,
    float* __restrict__ Acomp, float* __restrict__ Bcomp) {
    const int cg  = (blockIdx.x & 7) * 256 + threadIdx.x;   // 2048 col-groups/chunk
    const int ch  = blockIdx.x >> 3;
    const int col = cg * 4;
    const long base = (long)ch * CHL * NCOL + col;
    float Ax = 1.f, Ay = 1.f, Az = 1.f, Aw = 1.f;
    float Bx = 0.f, By = 0.f, Bz = 0.f, Bw = 0.f;
    const int U = 8;
    for (int w0 = 0; w0 < CHL; w0 += U) {
        u16x4 zr[U], fr[U];
#pragma unroll
        for (int u = 0; u < U; ++u) {
            const long idx = base + (long)(w0 + u) * NCOL;
            zr[u] = *(const u16x4*)(zb + idx);
            fr[u] = *(const u16x4*)(fb + idx);
        }
#pragma unroll
        for (int u = 0; u < U; ++u) {
            scan_step(bf2f(zr[u][0]), bf2f(fr[u][0]), Ax, Bx);
            scan_step(bf2f(zr[u][1]), bf2f(fr[u][1]), Ay, By);
            scan_step(bf2f(zr[u][2]), bf2f(fr[u][2]), Az, Bz);
            scan_step(bf2f(zr[u][3]), bf2f(fr[u][3]), Aw, Bw);
        }
    }
    *(f32x4*)(Acomp + (long)ch * NCOL + col) = (f32x4){Ax, Ay, Az, Aw};
    *(f32x4*)(Bcomp + (long)ch * NCOL + col) = (f32x4){Bx, By, Bz, Bw};
}

__global__ __launch_bounds__(256) void scan_apply(
    const ushort_t* __restrict__ zb, const ushort_t* __restrict__ fb,
    const ushort_t* __restrict__ ob,
    const float* __restrict__ Acomp, const float* __restrict__ Bcomp,
    float* __restrict__ out) {
    const int cg  = (blockIdx.x & 7) * 256 + threadIdx.x;
    const int ch  = blockIdx.x >> 3;
    const int col = cg * 4;
    const long base = (long)ch * CHL * NCOL + col;

    // local exclusive prefix over the chunk-compose results (L2-hit; 2 MB total)
    float cx = 0.f, cy = 0.f, cz = 0.f, cw = 0.f;
    for (int k = 0; k < ch; ++k) {
        f32x4 a4 = *(const f32x4*)(Acomp + (long)k * NCOL + col);
        f32x4 b4 = *(const f32x4*)(Bcomp + (long)k * NCOL + col);
        cx = a4[0] * cx + b4[0];
        cy = a4[1] * cy + b4[1];
        cz = a4[2] * cz + b4[2];
        cw = a4[3] * cw + b4[3];
    }

    float hx = 0.f, hy = 0.f, hz = 0.f, hw = 0.f;
    const int U = 8;
    for (int w0 = 0; w0 < CHL; w0 += U) {
        u16x4 zr[U], fr[U], orr[U];
#pragma unroll
        for (int u = 0; u < U; ++u) {
            const long idx = base + (long)(w0 + u) * NCOL;
            zr[u]  = ntload_u4(zb + idx);
            fr[u]  = ntload_u4(fb + idx);
            orr[u] = ntload_u4(ob + idx);
        }
#pragma unroll
        for (int u = 0; u < U; ++u) {
            float f, z;
            f = bf2f(fr[u][0]); z = bf2f(zr[u][0]); cx = f * cx + (1.f - f) * z; hx = cx * bf2f(orr[u][0]);
            f = bf2f(fr[u][1]); z = bf2f(zr[u][1]); cy = f * cy + (1.f - f) * z; hy = cy * bf2f(orr[u][1]);
            f = bf2f(fr[u][2]); z = bf2f(zr[u][2]); cz = f * cz + (1.f - f) * z; hz = cz * bf2f(orr[u][2]);
            f = bf2f(fr[u][3]); z = bf2f(zr[u][3]); cw = f * cw + (1.f - f) * z; hw = cw * bf2f(orr[u][3]);
            f32x4 hv = (f32x4){hx, hy, hz, hw};
            __builtin_nontemporal_store(hv, (f32x4*)(out + base + (long)(w0 + u) * NCOL));
        }
    }
    if (ch == NCH - 1) {
        *(f32x4*)(out + (long)SEQ * NCOL + col)        = (f32x4){hx, hy, hz, hw};  // h_last
        *(f32x4*)(out + (long)SEQ * NCOL + NCOL + col) = (f32x4){cx, cy, cz, cw};  // c_last
    }
}

// ---------------------------------------------------------------------------
extern "C" void kernel_launch(void* const* d_in, const int* in_sizes, int n_in,
                              void* d_out, int out_size, void* d_ws, size_t ws_size,
                              hipStream_t stream) {
    const float* x  = (const float*)d_in[0];   // (T, B, Cin)
    const float* W  = (const float*)d_in[1];   // (3H, Cin, 2)
    const float* bi = (const float*)d_in[2];   // (3H,)
    float* out = (float*)d_out;

    char* ws = (char*)d_ws;
    const size_t xbN = (size_t)(TBM + BATCH) * CINCH;   // padded bf16 x
    const size_t wbN = (size_t)NDIM * KRED;
    const size_t gN  = (size_t)TBM * HDIM;
    ushort_t* xb = (ushort_t*)ws;
    ushort_t* wb = (ushort_t*)(ws + xbN * 2);
    ushort_t* zb = (ushort_t*)(ws + xbN * 2 + wbN * 2);
    ushort_t* fb = zb + gN;
    ushort_t* ob = fb + gN;
    // scan scratch reuses the xb region (dead after the GEMM): 2 MB << 33.5 MB
    float* Acomp = (float*)ws;
    float* Bcomp = Acomp + NCH * NCOL;

    prep_kernel<<<CAST_BLOCKS + 6144, 256, 0, stream>>>(x, xb, W, wb);
    gemm_gates_kernel<<<768, 512, 0, stream>>>(xb, wb, bi, zb, fb, ob);
    scan_compose<<<NCH * 8, 256, 0, stream>>>(zb, fb, Acomp, Bcomp);
    scan_apply<<<NCH * 8, 256, 0, stream>>>(zb, fb, ob, Acomp, Bcomp, out);
}

// Round 12
// 272.754 us; speedup vs baseline: 1.2278x; 1.2278x over previous
//
#include <hip/hip_runtime.h>

// Problem constants
#define SEQ   2048
#define BATCH 16
#define CINCH 512
#define HDIM  512
#define NDIM  1536            // 3*H
#define TBM   (SEQ*BATCH)     // 32768 = GEMM M
#define KRED  1024            // Cin*K = GEMM K
#define NCH   32              // scan chunks (R2-proven; NCH=64 measured worse)
#define CHL   64              // chunk length (NCH*CHL == SEQ)
#define NCOL  8192            // B*H chains

typedef unsigned short ushort_t;
typedef __bf16 bf16x8 __attribute__((ext_vector_type(8)));
typedef unsigned short u16x8 __attribute__((ext_vector_type(8)));
typedef unsigned short u16x4 __attribute__((ext_vector_type(4)));
typedef float f32x4 __attribute__((ext_vector_type(4)));

__device__ __forceinline__ float bf2f(ushort_t u) {
    return __uint_as_float(((unsigned int)u) << 16);
}
__device__ __forceinline__ ushort_t f2bf(float x) {
    unsigned int u = __float_as_uint(x);
    unsigned int r = u + 0x7fffu + ((u >> 16) & 1u);   // round-to-nearest-even
    return (ushort_t)(r >> 16);
}

// ---------------------------------------------------------------------------
// Kernel 1: fused prep — cast x (fp32 -> bf16, with BATCH*CINCH zero prefix)
// and repack W (3H, Cin, 2) -> Wb (3H, 1024), one launch. x/W are last-use
// reads -> nontemporal.
// ---------------------------------------------------------------------------
#define CAST_BLOCKS 16392
__global__ void prep_kernel(const float* __restrict__ x, ushort_t* __restrict__ xb,
                            const float* __restrict__ W, ushort_t* __restrict__ wb) {
    if (blockIdx.x < CAST_BLOCKS) {
        int i = blockIdx.x * 256 + threadIdx.x;
        int e = i * 4;
        ushort4 r;
        if (e < BATCH * CINCH) {
            r.x = 0; r.y = 0; r.z = 0; r.w = 0;
        } else {
            f32x4 v = __builtin_nontemporal_load((const f32x4*)(x + (e - BATCH * CINCH)));
            r.x = f2bf(v[0]); r.y = f2bf(v[1]); r.z = f2bf(v[2]); r.w = f2bf(v[3]);
        }
        *(ushort4*)(xb + e) = r;
    } else {
        int i = (blockIdx.x - CAST_BLOCKS) * 256 + threadIdx.x;
        int o  = i >> 10;
        int r  = i & 1023;
        int k  = r >> 9;
        int ci = r & 511;
        wb[i] = f2bf(__builtin_nontemporal_load(W + o * 1024 + ci * 2 + k));
    }
}

// ---------------------------------------------------------------------------
// Kernel 2: GEMM + bias + activation -> bf16 gates z/f/o, each [T*B][H].
// CHAMPION (R10: GEMM 126.3 us, MfmaUtil 36.4%, FETCH 66 MB): 128x128 tile,
// BK=64, 4 waves, 16x16x32 MFMA, XOR-swizzled LDS, global_load_lds width=16
// for BOTH A and B, XCD-chunked N-fastest block swizzle.
// DO NOT RESTRUCTURE — measured-failed alternatives:
//   256^2 8-phase (R2: 138), B-in-reg 256^2 (R4: 204), B-in-reg 128^2
//   (R5: 286), 256^2 champion-schedule (R11: 191, reg-bound 1 block/CU).
// The 2-barrier schedule needs >=2 resident blocks/CU for wave-level overlap;
// 128^2 @ 4 waves (84 VGPR + 64 AGPR) is the proven operating point.
// ---------------------------------------------------------------------------
__device__ __forceinline__ void load_lds_16B(const ushort_t* g, ushort_t* l) {
    auto* gp = reinterpret_cast<const __attribute__((address_space(1))) unsigned int*>(
        reinterpret_cast<uintptr_t>(g));
    auto* lp = reinterpret_cast<__attribute__((address_space(3))) unsigned int*>(
        reinterpret_cast<uintptr_t>(l));
    __builtin_amdgcn_global_load_lds(gp, lp, 16, 0, 0);
}

__global__ __launch_bounds__(256) void gemm_gates_kernel(
    const ushort_t* __restrict__ xb, const ushort_t* __restrict__ wb,
    const float* __restrict__ bias,
    ushort_t* __restrict__ zb, ushort_t* __restrict__ fb, ushort_t* __restrict__ ob) {

    __shared__ ushort_t smem[2 * 128 * 64];   // As/Bs during K-loop; 128x128 out-tile in epilogue
    ushort_t* As = smem;
    ushort_t* Bs = smem + 128 * 64;

    const int tid  = threadIdx.x;
    const int w    = tid >> 6;
    const int lane = tid & 63;
    const int quad = lane >> 4;
    const int l15  = lane & 15;
    const int wm   = w & 1;
    const int wn   = w >> 1;

    // XCD-chunked bijective swizzle (3072 % 8 == 0), N-tile fastest in a chunk:
    // XCD k gets swz in [k*384,(k+1)*384) = 32 A-panels x 12 N-tiles each.
    const int bid = blockIdx.x;
    const int swz = (bid & 7) * 384 + (bid >> 3);
    const int mBase = (swz / 12) * 128;
    const int nBase = (swz % 12) * 128;

    const int srow = lane >> 3;
    const int scb  = lane & 7;

    f32x4 acc[4][4];
#pragma unroll
    for (int i = 0; i < 4; ++i)
#pragma unroll
        for (int j = 0; j < 4; ++j)
            acc[i][j] = (f32x4){0.f, 0.f, 0.f, 0.f};

    for (int kt = 0; kt < 16; ++kt) {
        __syncthreads();
        const long aOff = (kt < 8) ? (long)kt * 64 : (long)16 * 512 + (long)(kt - 8) * 64;
#pragma unroll
        for (int i = 0; i < 4; ++i) {
            const int row = w * 32 + i * 8 + srow;
            const int cbd = scb ^ (row & 7);
            const ushort_t* ga = xb + (long)(mBase + row) * 512 + aOff + cbd * 8;
            load_lds_16B(ga, &As[(w * 32 + i * 8) * 64]);
            const ushort_t* gb = wb + (long)(nBase + row) * 1024 + kt * 64 + cbd * 8;
            load_lds_16B(gb, &Bs[(w * 32 + i * 8) * 64]);
        }
        __syncthreads();

#pragma unroll
        for (int ks = 0; ks < 2; ++ks) {
            bf16x8 af[4], bfr[4];
            const int cbd = ks * 4 + quad;
#pragma unroll
            for (int mt = 0; mt < 4; ++mt) {
                int ml  = wm * 64 + mt * 16 + l15;
                int off = ml * 64 + ((cbd ^ (ml & 7)) * 8);
                af[mt] = __builtin_bit_cast(bf16x8, *(const u16x8*)(&As[off]));
            }
#pragma unroll
            for (int nt = 0; nt < 4; ++nt) {
                int nl  = wn * 64 + nt * 16 + l15;
                int off = nl * 64 + ((cbd ^ (nl & 7)) * 8);
                bfr[nt] = __builtin_bit_cast(bf16x8, *(const u16x8*)(&Bs[off]));
            }
#pragma unroll
            for (int mt = 0; mt < 4; ++mt)
#pragma unroll
                for (int nt = 0; nt < 4; ++nt)
                    acc[mt][nt] = __builtin_amdgcn_mfma_f32_16x16x32_bf16(
                        af[mt], bfr[nt], acc[mt][nt], 0, 0, 0);
        }
    }

    // ---- Epilogue: bias + activation into LDS (swizzled), then coalesced stores
    const int gate = nBase >> 9;            // block-uniform: 4 N-tiles per gate
    const int hb   = nBase & 511;

    __syncthreads();   // everyone done reading As/Bs
#pragma unroll
    for (int nt = 0; nt < 4; ++nt) {
        const int n_local = wn * 64 + nt * 16 + l15;
        const float bv = bias[nBase + n_local];
#pragma unroll
        for (int mt = 0; mt < 4; ++mt) {
#pragma unroll
            for (int r = 0; r < 4; ++r) {
                const int m_local = wm * 64 + mt * 16 + quad * 4 + r;
                float g = acc[mt][nt][r] + bv;
                float a;
                if (gate == 0) {
                    float e = __expf(-2.f * fabsf(g));
                    float t = (1.f - e) / (1.f + e);
                    a = copysignf(t, g);
                } else {
                    a = 1.f / (1.f + __expf(-g));
                }
                const int phys = ((n_local >> 3) ^ (m_local & 7)) * 8 + (n_local & 7);
                smem[m_local * 128 + phys] = f2bf(a);
            }
        }
    }
    __syncthreads();

    ushort_t* outp = (gate == 0) ? zb : (gate == 1) ? fb : ob;
#pragma unroll
    for (int s = 0; s < 8; ++s) {
        const int m_local = w * 32 + s * 4 + quad;
        const int blk = l15 ^ (m_local & 7);   // phys block holding logical block l15
        u16x8 v = *(const u16x8*)(&smem[m_local * 128 + blk * 8]);
        *(u16x8*)(outp + (long)(mBase + m_local) * 512 + hb + l15 * 8) = v;
    }
}

// ---------------------------------------------------------------------------
// Scan, chunked-parallel, TWO passes (prefix fused into apply):
//   compose: per-chunk (A,B) composition -> Acomp/Bcomp (2 MB, L2-resident)
//   apply:   local exclusive prefix over Acomp/Bcomp (<=31 L2-hit steps),
//            then apply+write. apply loads/stores nontemporal (last use).
// ---------------------------------------------------------------------------
__device__ __forceinline__ void scan_step(float z, float f, float& A, float& Bv) {
    Bv = f * Bv + (1.f - f) * z;
    A *= f;
}

__device__ __forceinline__ u16x4 ntload_u4(const ushort_t* p) {
    return __builtin_nontemporal_load((const u16x4*)p);
}

__global__ __launch_bounds__(256) void scan_compose(
    const ushort_t* __restrict__ zb, const ushort_t* __restrict__ fb,
    float* __restrict__ Acomp, float* __restrict__ Bcomp) {
    const int cg  = (blockIdx.x & 7) * 256 + threadIdx.x;   // 2048 col-groups/chunk
    const int ch  = blockIdx.x >> 3;
    const int col = cg * 4;
    const long base = (long)ch * CHL * NCOL + col;
    float Ax = 1.f, Ay = 1.f, Az = 1.f, Aw = 1.f;
    float Bx = 0.f, By = 0.f, Bz = 0.f, Bw = 0.f;
    const int U = 8;
    for (int w0 = 0; w0 < CHL; w0 += U) {
        u16x4 zr[U], fr[U];
#pragma unroll
        for (int u = 0; u < U; ++u) {
            const long idx = base + (long)(w0 + u) * NCOL;
            zr[u] = *(const u16x4*)(zb + idx);
            fr[u] = *(const u16x4*)(fb + idx);
        }
#pragma unroll
        for (int u = 0; u < U; ++u) {
            scan_step(bf2f(zr[u][0]), bf2f(fr[u][0]), Ax, Bx);
            scan_step(bf2f(zr[u][1]), bf2f(fr[u][1]), Ay, By);
            scan_step(bf2f(zr[u][2]), bf2f(fr[u][2]), Az, Bz);
            scan_step(bf2f(zr[u][3]), bf2f(fr[u][3]), Aw, Bw);
        }
    }
    *(f32x4*)(Acomp + (long)ch * NCOL + col) = (f32x4){Ax, Ay, Az, Aw};
    *(f32x4*)(Bcomp + (long)ch * NCOL + col) = (f32x4){Bx, By, Bz, Bw};
}

__global__ __launch_bounds__(256) void scan_apply(
    const ushort_t* __restrict__ zb, const ushort_t* __restrict__ fb,
    const ushort_t* __restrict__ ob,
    const float* __restrict__ Acomp, const float* __restrict__ Bcomp,
    float* __restrict__ out) {
    const int cg  = (blockIdx.x & 7) * 256 + threadIdx.x;
    const int ch  = blockIdx.x >> 3;
    const int col = cg * 4;
    const long base = (long)ch * CHL * NCOL + col;

    // local exclusive prefix over the chunk-compose results (L2-hit; 2 MB total)
    float cx = 0.f, cy = 0.f, cz = 0.f, cw = 0.f;
    for (int k = 0; k < ch; ++k) {
        f32x4 a4 = *(const f32x4*)(Acomp + (long)k * NCOL + col);
        f32x4 b4 = *(const f32x4*)(Bcomp + (long)k * NCOL + col);
        cx = a4[0] * cx + b4[0];
        cy = a4[1] * cy + b4[1];
        cz = a4[2] * cz + b4[2];
        cw = a4[3] * cw + b4[3];
    }

    float hx = 0.f, hy = 0.f, hz = 0.f, hw = 0.f;
    const int U = 8;
    for (int w0 = 0; w0 < CHL; w0 += U) {
        u16x4 zr[U], fr[U], orr[U];
#pragma unroll
        for (int u = 0; u < U; ++u) {
            const long idx = base + (long)(w0 + u) * NCOL;
            zr[u]  = ntload_u4(zb + idx);
            fr[u]  = ntload_u4(fb + idx);
            orr[u] = ntload_u4(ob + idx);
        }
#pragma unroll
        for (int u = 0; u < U; ++u) {
            float f, z;
            f = bf2f(fr[u][0]); z = bf2f(zr[u][0]); cx = f * cx + (1.f - f) * z; hx = cx * bf2f(orr[u][0]);
            f = bf2f(fr[u][1]); z = bf2f(zr[u][1]); cy = f * cy + (1.f - f) * z; hy = cy * bf2f(orr[u][1]);
            f = bf2f(fr[u][2]); z = bf2f(zr[u][2]); cz = f * cz + (1.f - f) * z; hz = cz * bf2f(orr[u][2]);
            f = bf2f(fr[u][3]); z = bf2f(zr[u][3]); cw = f * cw + (1.f - f) * z; hw = cw * bf2f(orr[u][3]);
            f32x4 hv = (f32x4){hx, hy, hz, hw};
            __builtin_nontemporal_store(hv, (f32x4*)(out + base + (long)(w0 + u) * NCOL));
        }
    }
    if (ch == NCH - 1) {
        *(f32x4*)(out + (long)SEQ * NCOL + col)        = (f32x4){hx, hy, hz, hw};  // h_last
        *(f32x4*)(out + (long)SEQ * NCOL + NCOL + col) = (f32x4){cx, cy, cz, cw};  // c_last
    }
}

// ---------------------------------------------------------------------------
extern "C" void kernel_launch(void* const* d_in, const int* in_sizes, int n_in,
                              void* d_out, int out_size, void* d_ws, size_t ws_size,
                              hipStream_t stream) {
    const float* x  = (const float*)d_in[0];   // (T, B, Cin)
    const float* W  = (const float*)d_in[1];   // (3H, Cin, 2)
    const float* bi = (const float*)d_in[2];   // (3H,)
    float* out = (float*)d_out;

    char* ws = (char*)d_ws;
    const size_t xbN = (size_t)(TBM + BATCH) * CINCH;   // padded bf16 x
    const size_t wbN = (size_t)NDIM * KRED;
    const size_t gN  = (size_t)TBM * HDIM;
    ushort_t* xb = (ushort_t*)ws;
    ushort_t* wb = (ushort_t*)(ws + xbN * 2);
    ushort_t* zb = (ushort_t*)(ws + xbN * 2 + wbN * 2);
    ushort_t* fb = zb + gN;
    ushort_t* ob = fb + gN;
    // scan scratch reuses the xb region (dead after the GEMM): 2 MB << 33.5 MB
    float* Acomp = (float*)ws;
    float* Bcomp = Acomp + NCH * NCOL;

    prep_kernel<<<CAST_BLOCKS + 6144, 256, 0, stream>>>(x, xb, W, wb);
    gemm_gates_kernel<<<3072, 256, 0, stream>>>(xb, wb, bi, zb, fb, ob);
    scan_compose<<<NCH * 8, 256, 0, stream>>>(zb, fb, Acomp, Bcomp);
    scan_apply<<<NCH * 8, 256, 0, stream>>>(zb, fb, ob, Acomp, Bcomp, out);
}